// Round 1
// baseline (452.717 us; speedup 1.0000x reference)
//
#include <hip/hip_runtime.h>

// X: (16, 64, 256, 256) fp32, K: (3,3) fp32, same-shape output.
// Depthwise 3x3, stride 1, pad 1. Purely HBM-bound (AI ~2.25 flop/byte).

#define CONV_H 256
#define CONV_W 256
#define CONV_W4 64          // float4 groups per row
#define NPLANES (16 * 64)   // B*C independent planes

__global__ __launch_bounds__(256)
void conv3x3_kernel(const float* __restrict__ X,
                    const float* __restrict__ Kw,
                    float* __restrict__ out)
{
    // 3x3 weights: all lanes read same cache line -> broadcast from L1.
    const float k00 = Kw[0], k01 = Kw[1], k02 = Kw[2];
    const float k10 = Kw[3], k11 = Kw[4], k12 = Kw[5];
    const float k20 = Kw[6], k21 = Kw[7], k22 = Kw[8];

    const int idx = blockIdx.x * blockDim.x + threadIdx.x;   // one float4 of output
    const int w4 = idx & (CONV_W4 - 1);        // [0,64)
    const int h  = (idx >> 6) & (CONV_H - 1);  // [0,256)
    const int p  = idx >> 14;                  // plane [0,1024)

    const float* plane = X + (size_t)p * (CONV_H * CONV_W);
    const int col0 = w4 << 2;

    float acc0 = 0.f, acc1 = 0.f, acc2 = 0.f, acc3 = 0.f;

    #pragma unroll
    for (int dr = -1; dr <= 1; ++dr) {
        const int r = h + dr;
        float4 c = make_float4(0.f, 0.f, 0.f, 0.f);
        float  l = 0.f, rt = 0.f;
        if (r >= 0 && r < CONV_H) {
            const float* rowp = plane + r * CONV_W + col0;
            c = *(const float4*)rowp;                 // aligned 16B load
            if (w4 > 0)           l  = rowp[-1];      // left edge elem (L1 hit)
            if (w4 < CONV_W4 - 1) rt = rowp[4];       // right edge elem (L1 hit)
        }
        float ka, kb, kc;
        if (dr == -1)      { ka = k00; kb = k01; kc = k02; }
        else if (dr == 0)  { ka = k10; kb = k11; kc = k12; }
        else               { ka = k20; kb = k21; kc = k22; }
        acc0 += ka * l   + kb * c.x + kc * c.y;
        acc1 += ka * c.x + kb * c.y + kc * c.z;
        acc2 += ka * c.y + kb * c.z + kc * c.w;
        acc3 += ka * c.z + kb * c.w + kc * rt;
    }

    *(float4*)(out + (size_t)idx * 4) = make_float4(acc0, acc1, acc2, acc3);
}

extern "C" void kernel_launch(void* const* d_in, const int* in_sizes, int n_in,
                              void* d_out, int out_size, void* d_ws, size_t ws_size,
                              hipStream_t stream) {
    const float* X  = (const float*)d_in[0];
    const float* Kw = (const float*)d_in[1];
    float* out = (float*)d_out;

    const int total_f4 = NPLANES * CONV_H * CONV_W4;  // 16,777,216
    const int block = 256;
    const int grid = total_f4 / block;                 // 65,536
    conv3x3_kernel<<<grid, block, 0, stream>>>(X, Kw, out);
}

// Round 2
// 450.734 us; speedup vs baseline: 1.0044x; 1.0044x over previous
//
#include <hip/hip_runtime.h>

// X: (16, 64, 256, 256) fp32, K: (3,3) fp32, same-shape output.
// Depthwise 3x3, stride 1, pad 1. HBM-bound: floor = 537 MB @ 6.3 TB/s ~ 85 us.
// R1: 8-row register blocking (rolling 3-row window, 1.25x read amp) +
//     XCD-chunk block swizzle (boundary rows reused in same XCD L2).

#define CONV_H 256
#define CONV_W 256
#define CONV_W4 64          // float4 groups per row
#define NPLANES (16 * 64)   // B*C independent planes
#define ROWS_PER_THREAD 8

struct Row { float4 c; float l, r; };

__device__ __forceinline__ Row load_row(const float* __restrict__ rowp, int w4) {
    Row v;
    v.c = *(const float4*)rowp;                    // aligned 16B load
    v.l = (w4 > 0)            ? rowp[-1] : 0.f;    // left pad at col 0
    v.r = (w4 < CONV_W4 - 1)  ? rowp[4]  : 0.f;    // right pad at col 255
    return v;
}

__device__ __forceinline__ Row zero_row() {
    Row v;
    v.c = make_float4(0.f, 0.f, 0.f, 0.f);
    v.l = 0.f; v.r = 0.f;
    return v;
}

__global__ __launch_bounds__(256)
void conv3x3_kernel(const float* __restrict__ X,
                    const float* __restrict__ Kw,
                    float* __restrict__ out)
{
    const float k00 = Kw[0], k01 = Kw[1], k02 = Kw[2];
    const float k10 = Kw[3], k11 = Kw[4], k12 = Kw[5];
    const float k20 = Kw[6], k21 = Kw[7], k22 = Kw[8];

    // XCD swizzle: physical blocks b with b%8==x go to XCD x; remap so each
    // XCD owns a contiguous 1/8 chunk of logical block space (adjacent
    // stripes -> same XCD L2 -> boundary rows fetched once).
    const int chunk = gridDim.x >> 3;                       // 1024
    const int lb = (blockIdx.x & 7) * chunk + (blockIdx.x >> 3);

    const int tid    = lb * blockDim.x + threadIdx.x;
    const int w4     = tid & (CONV_W4 - 1);                 // lane-contiguous -> coalesced
    const int stripe = tid >> 6;                            // 8-row stripe id
    const int h0     = (stripe & 31) << 3;                  // 0,8,...,248
    const int p      = stripe >> 5;                         // plane

    const float* plane = X + (size_t)p * (CONV_H * CONV_W);
    const int col0 = w4 << 2;
    float* outp = out + (size_t)p * (CONV_H * CONV_W) + (size_t)h0 * CONV_W + col0;

    // rolling window: rm = row h-1, rc = row h, rp = row h+1
    Row rm = (h0 > 0) ? load_row(plane + (h0 - 1) * CONV_W + col0, w4) : zero_row();
    Row rc = load_row(plane + h0 * CONV_W + col0, w4);

    #pragma unroll
    for (int i = 0; i < ROWS_PER_THREAD; ++i) {
        const int hp = h0 + i + 1;
        Row rp = (hp < CONV_H) ? load_row(plane + hp * CONV_W + col0, w4)
                               : zero_row();

        float4 o;
        o.x = k00 * rm.l   + k01 * rm.c.x + k02 * rm.c.y
            + k10 * rc.l   + k11 * rc.c.x + k12 * rc.c.y
            + k20 * rp.l   + k21 * rp.c.x + k22 * rp.c.y;
        o.y = k00 * rm.c.x + k01 * rm.c.y + k02 * rm.c.z
            + k10 * rc.c.x + k11 * rc.c.y + k12 * rc.c.z
            + k20 * rp.c.x + k21 * rp.c.y + k22 * rp.c.z;
        o.z = k00 * rm.c.y + k01 * rm.c.z + k02 * rm.c.w
            + k10 * rc.c.y + k11 * rc.c.z + k12 * rc.c.w
            + k20 * rp.c.y + k21 * rp.c.z + k22 * rp.c.w;
        o.w = k00 * rm.c.z + k01 * rm.c.w + k02 * rm.r
            + k10 * rc.c.z + k11 * rc.c.w + k12 * rc.r
            + k20 * rp.c.z + k21 * rp.c.w + k22 * rp.r;

        *(float4*)(outp + i * CONV_W) = o;

        rm = rc;
        rc = rp;
    }
}

extern "C" void kernel_launch(void* const* d_in, const int* in_sizes, int n_in,
                              void* d_out, int out_size, void* d_ws, size_t ws_size,
                              hipStream_t stream) {
    const float* X  = (const float*)d_in[0];
    const float* Kw = (const float*)d_in[1];
    float* out = (float*)d_out;

    // one thread per (8 rows x 4 cols): 1024 planes * 32 stripes * 64 lanes
    const int total_threads = NPLANES * (CONV_H / ROWS_PER_THREAD) * CONV_W4; // 2,097,152
    const int block = 256;
    const int grid = total_threads / block;                                   // 8192
    conv3x3_kernel<<<grid, block, 0, stream>>>(X, Kw, out);
}